// Round 2
// baseline (233.761 us; speedup 1.0000x reference)
//
#include <hip/hip_runtime.h>
#include <math.h>

// GlobalAttention, single-streaming-pass version.
//   logits[b,h,n] = qW[h,:].LN(x[b,n,:])  (q folded through Wkv_k, LN folded via mu/rstd)
//   s[b,h,:]      = sum_n softmax(logits) * rstd_n * x[b,n,:]  (flash-style online partials)
//   out           = cf + (Wkv_v @ (gamma*(S-UN)/E + beta)) @ proj_W.T + proj_b
// x (256 MB) is read exactly once by the fused kernel; partials merged deterministically.

#define BB 16
#define NN 4096
#define CC 1024
#define HH 8
#define DD 128
#define CHUNKS 32   // chunks per batch
#define RPB 128     // rows per block
#define TPT 8       // rows per tile
#define NT 16       // tiles per block

constexpr float EPS_ = 1e-5f;
constexpr float SCALE_ = 0.03125f; // 1024^-0.5

__device__ __forceinline__ float wsum(float v) {
#pragma unroll
  for (int o = 32; o; o >>= 1) v += __shfl_xor(v, o, 64);
  return v;
}

// DPP wave reduction: sum of all 64 lanes lands in lane 63 (VALU pipe, no LDS).
__device__ __forceinline__ float dpp_sum63(float v) {
  int t;
  t = __builtin_amdgcn_update_dpp(0, __float_as_int(v), 0x111, 0xf, 0xf, true);  v += __int_as_float(t);
  t = __builtin_amdgcn_update_dpp(0, __float_as_int(v), 0x112, 0xf, 0xf, true);  v += __int_as_float(t);
  t = __builtin_amdgcn_update_dpp(0, __float_as_int(v), 0x114, 0xf, 0xf, true);  v += __int_as_float(t);
  t = __builtin_amdgcn_update_dpp(0, __float_as_int(v), 0x118, 0xf, 0xf, true);  v += __int_as_float(t);
  t = __builtin_amdgcn_update_dpp(0, __float_as_int(v), 0x142, 0xa, 0xf, false); v += __int_as_float(t);
  t = __builtin_amdgcn_update_dpp(0, __float_as_int(v), 0x143, 0xc, 0xf, false); v += __int_as_float(t);
  return v;
}

// barrier without vmcnt drain (keeps prefetch loads in flight)
__device__ __forceinline__ void bar_lgkm() {
  asm volatile("s_waitcnt lgkmcnt(0)" ::: "memory");
  __builtin_amdgcn_sched_barrier(0);
  __builtin_amdgcn_s_barrier();
  __builtin_amdgcn_sched_barrier(0);
}

__device__ __forceinline__ float dot4(const float4& a, const float4& b) {
  return a.x * b.x + a.y * b.y + a.z * b.z + a.w * b.w;
}
__device__ __forceinline__ void fma4(float4& a, float s, const float4& v) {
  a.x += s * v.x; a.y += s * v.y; a.z += s * v.z; a.w += s * v.w;
}

// ---- k0a: LN(class_feature) -> ln_cf [1024] ----
__global__ __launch_bounds__(256) void k0a(const float* __restrict__ cf,
                                           const float* __restrict__ g,
                                           const float* __restrict__ be,
                                           float* __restrict__ ln_cf) {
  int t = threadIdx.x, lane = t & 63, wid = t >> 6;
  float x[4];
  float s = 0.f, s2 = 0.f;
#pragma unroll
  for (int j = 0; j < 4; ++j) {
    x[j] = cf[t * 4 + j];
    s += x[j];
    s2 += x[j] * x[j];
  }
  __shared__ float red[8];
  s = wsum(s);
  s2 = wsum(s2);
  if (lane == 0) { red[wid] = s; red[4 + wid] = s2; }
  __syncthreads();
  float S = red[0] + red[1] + red[2] + red[3];
  float S2 = red[4] + red[5] + red[6] + red[7];
  float mu = S * (1.f / CC);
  float rstd = rsqrtf(S2 * (1.f / CC) - mu * mu + EPS_);
#pragma unroll
  for (int j = 0; j < 4; ++j)
    ln_cf[t * 4 + j] = (x[j] - mu) * rstd * g[t * 4 + j] + be[t * 4 + j];
}

// ---- k0b: qvec[j] = ln_cf . Wq[j,:] ----
__global__ __launch_bounds__(256) void k0b(const float* __restrict__ ln_cf,
                                           const float* __restrict__ Wq,
                                           float* __restrict__ qvec) {
  int lane = threadIdx.x & 63;
  int j = blockIdx.x * 4 + (threadIdx.x >> 6);
  const float4* wr = (const float4*)(Wq + (size_t)j * CC);
  const float4* l4 = (const float4*)ln_cf;
  float a = 0.f;
#pragma unroll
  for (int k = 0; k < 4; ++k) {
    float4 w = wr[lane + 64 * k], l = l4[lane + 64 * k];
    a += dot4(w, l);
  }
  a = wsum(a);
  if (lane == 0) qvec[j] = a;
}

// ---- k0c: qW[h,c] = scale*sum_d qvec[h*D+d]*Wkv[h*D+d,c]; qWg = qW*gamma ----
__global__ __launch_bounds__(256) void k0c(const float* __restrict__ qvec,
                                           const float* __restrict__ Wkv,
                                           const float* __restrict__ kvg,
                                           float* __restrict__ qW,
                                           float* __restrict__ qWg) {
  int h = blockIdx.x >> 4;
  int c0 = (blockIdx.x & 15) * 64;
  int t = threadIdx.x, cl = t & 63, g = t >> 6;
  float a = 0.f;
#pragma unroll 8
  for (int d = g * 32; d < g * 32 + 32; ++d)
    a += qvec[h * DD + d] * Wkv[((size_t)(h * DD + d)) * CC + c0 + cl];
  __shared__ float red[4][64];
  red[g][cl] = a;
  __syncthreads();
  if (t < 64) {
    float v = (red[0][t] + red[1][t] + red[2][t] + red[3][t]) * SCALE_;
    qW[h * CC + c0 + t] = v;
    qWg[h * CC + c0 + t] = v * kvg[c0 + t];
  }
}

// ---- k0d: qWgs[h] = sum_c qWg[h,c];  qWb[h] = sum_c qW[h,c]*beta[c] ----
__global__ __launch_bounds__(256) void k0d(const float* __restrict__ qW,
                                           const float* __restrict__ qWg,
                                           const float* __restrict__ kvb,
                                           float* __restrict__ qWgs,
                                           float* __restrict__ qWb) {
  int h = blockIdx.x, t = threadIdx.x, lane = t & 63, wid = t >> 6;
  float gs = 0.f, bb = 0.f;
  for (int c = t; c < CC; c += 256) {
    gs += qWg[h * CC + c];
    bb += qW[h * CC + c] * kvb[c];
  }
  gs = wsum(gs);
  bb = wsum(bb);
  __shared__ float red[8];
  if (lane == 0) { red[wid] = gs; red[4 + wid] = bb; }
  __syncthreads();
  if (t == 0) {
    qWgs[h] = red[0] + red[1] + red[2] + red[3];
    qWb[h] = red[4] + red[5] + red[6] + red[7];
  }
}

// ---- fused: single pass over x. Per block: 128 rows of one batch.
//   tile loop (8 rows): [prefetch next tile to regs] -> dot phase (LDS x, qW regs,
//   DPP reductions) -> W phase (wave0: logits->exp, online m/e/un, defer-max) ->
//   ACC phase (thread owns 4 cols x 8 heads) -> ds_write prefetched tile.
__global__ __launch_bounds__(256, 2) void kfused(
    const float* __restrict__ x, const float* __restrict__ qWg,
    const float* __restrict__ qWgs, const float* __restrict__ qWb,
    float* __restrict__ part_s, float* __restrict__ part_meu) {
  __shared__ __align__(16) float xbuf[TPT * CC];   // 32 KB
  __shared__ __align__(16) float dt_lds[TPT * HH];
  __shared__ __align__(16) float w_lds[TPT * HH];
  __shared__ __align__(16) float fac_lds[HH];
  __shared__ float mu_lds[TPT], rstd_lds[TPT];

  const int t = threadIdx.x, lane = t & 63, wid = t >> 6;
  const int chunk = blockIdx.x, b = blockIdx.y;
  const int bc = b * CHUNKS + chunk;
  const int h0 = wid * 2, h1 = h0 + 1;

  // this wave's two heads' qWg fragments (cols = 4*(lane+64k)..+3)
  float4 qw0[4], qw1[4];
  {
    const float4* a0 = (const float4*)(qWg + (size_t)h0 * CC);
    const float4* a1 = (const float4*)(qWg + (size_t)h1 * CC);
#pragma unroll
    for (int k = 0; k < 4; ++k) { qw0[k] = a0[lane + 64 * k]; qw1[k] = a1[lane + 64 * k]; }
  }
  float qs_h = 0.f, qb_h = 0.f;
  if (wid == 0 && lane < 8) { qs_h = qWgs[lane]; qb_h = qWb[lane]; }

  float4 acc[8];
#pragma unroll
  for (int h = 0; h < 8; ++h) acc[h] = make_float4(0.f, 0.f, 0.f, 0.f);
  float m_reg = -3.0e38f, e_reg = 0.f, un_reg = 0.f;

  const float4* gx = (const float4*)(x + ((size_t)b * NN + (size_t)chunk * RPB) * CC);
  float4* xb4 = (float4*)xbuf;

  // prologue: stage tile 0
  float4 stg[8];
#pragma unroll
  for (int k = 0; k < 8; ++k) stg[k] = gx[t + 256 * k];
#pragma unroll
  for (int k = 0; k < 8; ++k) xb4[t + 256 * k] = stg[k];
  __syncthreads();

  for (int tl = 0; tl < NT; ++tl) {
    // issue next tile's global loads (consumed at tile end; hides HBM latency)
    if (tl + 1 < NT) {
      const float4* gn = gx + (size_t)(tl + 1) * (TPT * CC / 4);
#pragma unroll
      for (int k = 0; k < 8; ++k) stg[k] = gn[t + 256 * k];
    }

    // ---- DOT phase: wave computes its 2 heads for all 8 rows; mu/rstd for its 2 rows
#pragma unroll
    for (int r = 0; r < TPT; ++r) {
      float4 x0 = xb4[r * 256 + lane];
      float4 x1 = xb4[r * 256 + lane + 64];
      float4 x2 = xb4[r * 256 + lane + 128];
      float4 x3 = xb4[r * 256 + lane + 192];
      float d0 = dot4(qw0[0], x0) + dot4(qw0[1], x1) + dot4(qw0[2], x2) + dot4(qw0[3], x3);
      float d1 = dot4(qw1[0], x0) + dot4(qw1[1], x1) + dot4(qw1[2], x2) + dot4(qw1[3], x3);
      d0 = dpp_sum63(d0);
      d1 = dpp_sum63(d1);
      if (lane == 63) { dt_lds[r * 8 + h0] = d0; dt_lds[r * 8 + h1] = d1; }
      if ((r >> 1) == wid) {
        float ls = (x0.x + x0.y + x0.z + x0.w) + (x1.x + x1.y + x1.z + x1.w) +
                   (x2.x + x2.y + x2.z + x2.w) + (x3.x + x3.y + x3.z + x3.w);
        float ls2 = dot4(x0, x0) + dot4(x1, x1) + dot4(x2, x2) + dot4(x3, x3);
        ls = dpp_sum63(ls);
        ls2 = dpp_sum63(ls2);
        if (lane == 63) {
          float mu = ls * (1.f / CC);
          float rs = rsqrtf(ls2 * (1.f / CC) - mu * mu + EPS_);
          mu_lds[r] = mu;
          rstd_lds[r] = rs;
        }
      }
    }
    bar_lgkm();

    // ---- W phase: wave0 lanes 0..7 (lane = head) finalize logits, online softmax
    if (wid == 0 && lane < 8) {
      float l[TPT];
      float tm = -3.0e38f;
#pragma unroll
      for (int r = 0; r < TPT; ++r) {
        l[r] = rstd_lds[r] * (dt_lds[r * 8 + lane] - mu_lds[r] * qs_h) + qb_h;
        tm = fmaxf(tm, l[r]);
      }
      float f = 1.f;
      if (tm > m_reg + 8.f) {  // defer-max: rescale only on big growth
        f = __expf(m_reg - tm);
        m_reg = tm;
        e_reg *= f;
        un_reg *= f;
      }
      fac_lds[lane] = f;
#pragma unroll
      for (int r = 0; r < TPT; ++r) {
        float p = __expf(l[r] - m_reg);
        float wv = p * rstd_lds[r];
        e_reg += p;
        un_reg += wv * mu_lds[r];
        w_lds[r * 8 + lane] = wv;
      }
    }
    bar_lgkm();

    // ---- ACC phase: all threads; thread owns cols 4t..4t+3, all 8 heads
    {
      float4 fA = *(const float4*)&fac_lds[0];
      float4 fB = *(const float4*)&fac_lds[4];
      acc[0].x *= fA.x; acc[0].y *= fA.x; acc[0].z *= fA.x; acc[0].w *= fA.x;
      acc[1].x *= fA.y; acc[1].y *= fA.y; acc[1].z *= fA.y; acc[1].w *= fA.y;
      acc[2].x *= fA.z; acc[2].y *= fA.z; acc[2].z *= fA.z; acc[2].w *= fA.z;
      acc[3].x *= fA.w; acc[3].y *= fA.w; acc[3].z *= fA.w; acc[3].w *= fA.w;
      acc[4].x *= fB.x; acc[4].y *= fB.x; acc[4].z *= fB.x; acc[4].w *= fB.x;
      acc[5].x *= fB.y; acc[5].y *= fB.y; acc[5].z *= fB.y; acc[5].w *= fB.y;
      acc[6].x *= fB.z; acc[6].y *= fB.z; acc[6].z *= fB.z; acc[6].w *= fB.z;
      acc[7].x *= fB.w; acc[7].y *= fB.w; acc[7].z *= fB.w; acc[7].w *= fB.w;
#pragma unroll
      for (int r = 0; r < TPT; ++r) {
        float4 xv = xb4[r * 256 + t];
        float4 wA = *(const float4*)&w_lds[r * 8];
        float4 wB = *(const float4*)&w_lds[r * 8 + 4];
        fma4(acc[0], wA.x, xv);
        fma4(acc[1], wA.y, xv);
        fma4(acc[2], wA.z, xv);
        fma4(acc[3], wA.w, xv);
        fma4(acc[4], wB.x, xv);
        fma4(acc[5], wB.y, xv);
        fma4(acc[6], wB.z, xv);
        fma4(acc[7], wB.w, xv);
      }
    }
    bar_lgkm();  // all xbuf reads done

    if (tl + 1 < NT) {
#pragma unroll
      for (int k = 0; k < 8; ++k) xb4[t + 256 * k] = stg[k];  // waits its own vmcnt
      bar_lgkm();  // writes visible to all
    }
  }

  // ---- store partials
  float4* ps = (float4*)(part_s + (size_t)bc * (HH * CC));
#pragma unroll
  for (int h = 0; h < 8; ++h) ps[h * 256 + t] = acc[h];
  if (wid == 0 && lane < 8) {
    float* pm = part_meu + ((size_t)bc * HH + lane) * 3;
    pm[0] = m_reg;
    pm[1] = e_reg;
    pm[2] = un_reg;
  }
}

// ---- merge partials: s[b,h,c] = gamma*(S-UN)/E + beta ----
__global__ __launch_bounds__(256) void kmerge(
    const float* __restrict__ part_s, const float* __restrict__ part_meu,
    const float* __restrict__ kvg, const float* __restrict__ kvb,
    float* __restrict__ s) {
  int h = blockIdx.x, b = blockIdx.y, t = threadIdx.x;
  float M = -3.0e38f;
  for (int ch = 0; ch < CHUNKS; ++ch)
    M = fmaxf(M, part_meu[(((size_t)b * CHUNKS + ch) * HH + h) * 3]);
  float E = 0.f, UN = 0.f;
  float4 a = make_float4(0.f, 0.f, 0.f, 0.f);
  for (int ch = 0; ch < CHUNKS; ++ch) {
    const float* pm = part_meu + (((size_t)b * CHUNKS + ch) * HH + h) * 3;
    float f = __expf(pm[0] - M);
    E += pm[1] * f;
    UN += pm[2] * f;
    float4 v = ((const float4*)(part_s + ((size_t)b * CHUNKS + ch) * (HH * CC) + h * CC))[t];
    fma4(a, f, v);
  }
  float inv = 1.f / E;
  float4 g = ((const float4*)kvg)[t];
  float4 be = ((const float4*)kvb)[t];
  float4 o;
  o.x = g.x * (a.x - UN) * inv + be.x;
  o.y = g.y * (a.y - UN) * inv + be.y;
  o.z = g.z * (a.z - UN) * inv + be.z;
  o.w = g.w * (a.w - UN) * inv + be.w;
  ((float4*)(s + ((size_t)b * HH + h) * CC))[t] = o;
}

// ---- k5: agg[b,j] = Wkv[C+j,:] . s[b, j/D, :] ----
__global__ __launch_bounds__(256) void k5(const float* __restrict__ Wkv,
                                          const float* __restrict__ s,
                                          float* __restrict__ agg) {
  int lane = threadIdx.x & 63;
  int j = blockIdx.x * 4 + (threadIdx.x >> 6);
  int h = j >> 7;
  const float4* wr = (const float4*)(Wkv + ((size_t)(CC + j)) * CC);
  float4 wv[4];
#pragma unroll
  for (int k = 0; k < 4; ++k) wv[k] = wr[lane + 64 * k];
  for (int b = 0; b < BB; ++b) {
    const float4* s4 = (const float4*)(s + ((size_t)(b * HH + h)) * CC);
    float a = 0.f;
#pragma unroll
    for (int k = 0; k < 4; ++k) a += dot4(wv[k], s4[lane + 64 * k]);
    a = wsum(a);
    if (lane == 0) agg[b * CC + j] = a;
  }
}

// ---- k6: out[b,j] = cf[j] + agg[b,:] . proj_W[j,:] + proj_b[j] ----
__global__ __launch_bounds__(256) void k6(const float* __restrict__ pW,
                                          const float* __restrict__ agg,
                                          const float* __restrict__ cf,
                                          const float* __restrict__ pb,
                                          float* __restrict__ out) {
  int lane = threadIdx.x & 63;
  int j = blockIdx.x * 4 + (threadIdx.x >> 6);
  const float4* wr = (const float4*)(pW + (size_t)j * CC);
  float4 wv[4];
#pragma unroll
  for (int k = 0; k < 4; ++k) wv[k] = wr[lane + 64 * k];
  for (int b = 0; b < BB; ++b) {
    const float4* a4 = (const float4*)(agg + (size_t)b * CC);
    float a = 0.f;
#pragma unroll
    for (int k = 0; k < 4; ++k) a += dot4(wv[k], a4[lane + 64 * k]);
    a = wsum(a);
    if (lane == 0) out[b * CC + j] = cf[j] + a + pb[j];
  }
}

// ws float offsets
constexpr size_t WS_LNCF = 0;        // 1024
constexpr size_t WS_QVEC = 1024;     // 1024
constexpr size_t WS_QW   = 2048;     // 8192
constexpr size_t WS_QWG  = 10240;    // 8192
constexpr size_t WS_QWGS = 18432;    // 8
constexpr size_t WS_QWB  = 18440;    // 8
constexpr size_t WS_S    = 18448;    // 131072
constexpr size_t WS_AGG  = 149520;   // 16384
constexpr size_t WS_PMEU = 165904;   // 12288
constexpr size_t WS_PART = 178192;   // 4194304 (16 MB)

extern "C" void kernel_launch(void* const* d_in, const int* in_sizes, int n_in,
                              void* d_out, int out_size, void* d_ws, size_t ws_size,
                              hipStream_t stream) {
  const float* cf = (const float*)d_in[0];
  const float* x = (const float*)d_in[1];
  const float* qg = (const float*)d_in[2];
  const float* qb = (const float*)d_in[3];
  const float* Wq = (const float*)d_in[4];
  const float* kvg = (const float*)d_in[5];
  const float* kvb = (const float*)d_in[6];
  const float* Wkv = (const float*)d_in[7];
  const float* pW = (const float*)d_in[8];
  const float* pb = (const float*)d_in[9];
  float* ws = (float*)d_ws;
  float* out = (float*)d_out;

  k0a<<<1, 256, 0, stream>>>(cf, qg, qb, ws + WS_LNCF);
  k0b<<<256, 256, 0, stream>>>(ws + WS_LNCF, Wq, ws + WS_QVEC);
  k0c<<<128, 256, 0, stream>>>(ws + WS_QVEC, Wkv, kvg, ws + WS_QW, ws + WS_QWG);
  k0d<<<8, 256, 0, stream>>>(ws + WS_QW, ws + WS_QWG, kvb, ws + WS_QWGS, ws + WS_QWB);
  kfused<<<dim3(CHUNKS, BB), 256, 0, stream>>>(x, ws + WS_QWG, ws + WS_QWGS,
                                               ws + WS_QWB, ws + WS_PART, ws + WS_PMEU);
  kmerge<<<dim3(HH, BB), 256, 0, stream>>>(ws + WS_PART, ws + WS_PMEU, kvg, kvb,
                                           ws + WS_S);
  k5<<<256, 256, 0, stream>>>(Wkv, ws + WS_S, ws + WS_AGG);
  k6<<<256, 256, 0, stream>>>(pW, ws + WS_AGG, cf, pb, out);
}

// Round 3
// 140.270 us; speedup vs baseline: 1.6665x; 1.6665x over previous
//
#include <hip/hip_runtime.h>
#include <math.h>

// GlobalAttention, single-streaming-pass version (v3).
//   logits[b,h,n] = qW[h,:].LN(x[b,n,:])  (q folded through Wkv_k, LN folded via mu/rstd)
//   s[b,h,:]      = sum_n softmax(logits) * rstd_n * x[b,n,:]  (flash-style online partials)
//   out           = cf + (Wkv_v @ (gamma*(S-UN)/E + beta)) @ proj_W.T + proj_b
// x (256 MB) read exactly once, staged via global_load_lds (no VGPR round-trip -> no spill).
// Per block: 64 rows, 16 tiles x 4 rows, double-buffered 16 KB LDS tiles, 4 blocks/CU.

#define BB 16
#define NN 4096
#define CC 1024
#define HH 8
#define DD 128
#define CHUNKS 64   // chunks per batch
#define RPB 64      // rows per block
#define TPT 4       // rows per tile
#define NT 16       // tiles per block

constexpr float EPS_ = 1e-5f;
constexpr float SCALE_ = 0.03125f; // 1024^-0.5

__device__ __forceinline__ float wsum(float v) {
#pragma unroll
  for (int o = 32; o; o >>= 1) v += __shfl_xor(v, o, 64);
  return v;
}

// DPP wave reduction: sum of all 64 lanes lands in lane 63 (VALU pipe, no LDS).
__device__ __forceinline__ float dpp_sum63(float v) {
  int t;
  t = __builtin_amdgcn_update_dpp(0, __float_as_int(v), 0x111, 0xf, 0xf, true);  v += __int_as_float(t);
  t = __builtin_amdgcn_update_dpp(0, __float_as_int(v), 0x112, 0xf, 0xf, true);  v += __int_as_float(t);
  t = __builtin_amdgcn_update_dpp(0, __float_as_int(v), 0x114, 0xf, 0xf, true);  v += __int_as_float(t);
  t = __builtin_amdgcn_update_dpp(0, __float_as_int(v), 0x118, 0xf, 0xf, true);  v += __int_as_float(t);
  t = __builtin_amdgcn_update_dpp(0, __float_as_int(v), 0x142, 0xa, 0xf, false); v += __int_as_float(t);
  t = __builtin_amdgcn_update_dpp(0, __float_as_int(v), 0x143, 0xc, 0xf, false); v += __int_as_float(t);
  return v;
}

// barrier that waits LDS ops only (keeps global_load_lds prefetch in flight)
__device__ __forceinline__ void bar_lgkm() {
  asm volatile("s_waitcnt lgkmcnt(0)" ::: "memory");
  __builtin_amdgcn_sched_barrier(0);
  __builtin_amdgcn_s_barrier();
  __builtin_amdgcn_sched_barrier(0);
}

// barrier that additionally drains vmcnt (top of tile loop: current tile ready)
__device__ __forceinline__ void bar_vm() {
  asm volatile("s_waitcnt vmcnt(0) lgkmcnt(0)" ::: "memory");
  __builtin_amdgcn_sched_barrier(0);
  __builtin_amdgcn_s_barrier();
  __builtin_amdgcn_sched_barrier(0);
}

__device__ __forceinline__ float dot4(const float4& a, const float4& b) {
  return a.x * b.x + a.y * b.y + a.z * b.z + a.w * b.w;
}
__device__ __forceinline__ void fma4(float4& a, float s, const float4& v) {
  a.x += s * v.x; a.y += s * v.y; a.z += s * v.z; a.w += s * v.w;
}
__device__ __forceinline__ void scl4(float4& a, float s) {
  a.x *= s; a.y *= s; a.z *= s; a.w *= s;
}

// stage one 4-row tile (16 KB) into LDS: 4 x global_load_lds dwordx4 per thread.
// LDS dest is wave-uniform base; HW adds lane*16 (linear layout both sides).
__device__ __forceinline__ void stage_tile(const float* gsrc, float* lbase,
                                           int wid, int lane) {
#pragma unroll
  for (int k = 0; k < 4; ++k) {
    const char* g = (const char*)gsrc + k * 4096 + wid * 1024 + lane * 16;
    char* l = (char*)lbase + k * 4096 + wid * 1024;
    __builtin_amdgcn_global_load_lds(
        (const __attribute__((address_space(1))) void*)g,
        (__attribute__((address_space(3))) void*)l, 16, 0, 0);
  }
}

// ---- k0a: LN(class_feature) -> ln_cf [1024] ----
__global__ __launch_bounds__(256) void k0a(const float* __restrict__ cf,
                                           const float* __restrict__ g,
                                           const float* __restrict__ be,
                                           float* __restrict__ ln_cf) {
  int t = threadIdx.x, lane = t & 63, wid = t >> 6;
  float x[4];
  float s = 0.f, s2 = 0.f;
#pragma unroll
  for (int j = 0; j < 4; ++j) {
    x[j] = cf[t * 4 + j];
    s += x[j];
    s2 += x[j] * x[j];
  }
  __shared__ float red[8];
  s = wsum(s);
  s2 = wsum(s2);
  if (lane == 0) { red[wid] = s; red[4 + wid] = s2; }
  __syncthreads();
  float S = red[0] + red[1] + red[2] + red[3];
  float S2 = red[4] + red[5] + red[6] + red[7];
  float mu = S * (1.f / CC);
  float rstd = rsqrtf(S2 * (1.f / CC) - mu * mu + EPS_);
#pragma unroll
  for (int j = 0; j < 4; ++j)
    ln_cf[t * 4 + j] = (x[j] - mu) * rstd * g[t * 4 + j] + be[t * 4 + j];
}

// ---- k0b: qvec[j] = ln_cf . Wq[j,:] ----
__global__ __launch_bounds__(256) void k0b(const float* __restrict__ ln_cf,
                                           const float* __restrict__ Wq,
                                           float* __restrict__ qvec) {
  int lane = threadIdx.x & 63;
  int j = blockIdx.x * 4 + (threadIdx.x >> 6);
  const float4* wr = (const float4*)(Wq + (size_t)j * CC);
  const float4* l4 = (const float4*)ln_cf;
  float a = 0.f;
#pragma unroll
  for (int k = 0; k < 4; ++k) {
    float4 w = wr[lane + 64 * k], l = l4[lane + 64 * k];
    a += dot4(w, l);
  }
  a = wsum(a);
  if (lane == 0) qvec[j] = a;
}

// ---- k0c: qW[h,c] = scale*sum_d qvec[h*D+d]*Wkv[h*D+d,c]; qWg = qW*gamma ----
__global__ __launch_bounds__(256) void k0c(const float* __restrict__ qvec,
                                           const float* __restrict__ Wkv,
                                           const float* __restrict__ kvg,
                                           float* __restrict__ qW,
                                           float* __restrict__ qWg) {
  int h = blockIdx.x >> 4;
  int c0 = (blockIdx.x & 15) * 64;
  int t = threadIdx.x, cl = t & 63, g = t >> 6;
  float a = 0.f;
#pragma unroll 8
  for (int d = g * 32; d < g * 32 + 32; ++d)
    a += qvec[h * DD + d] * Wkv[((size_t)(h * DD + d)) * CC + c0 + cl];
  __shared__ float red[4][64];
  red[g][cl] = a;
  __syncthreads();
  if (t < 64) {
    float v = (red[0][t] + red[1][t] + red[2][t] + red[3][t]) * SCALE_;
    qW[h * CC + c0 + t] = v;
    qWg[h * CC + c0 + t] = v * kvg[c0 + t];
  }
}

// ---- k0d: qWgs[h] = sum_c qWg[h,c];  qWb[h] = sum_c qW[h,c]*beta[c] ----
__global__ __launch_bounds__(256) void k0d(const float* __restrict__ qW,
                                           const float* __restrict__ qWg,
                                           const float* __restrict__ kvb,
                                           float* __restrict__ qWgs,
                                           float* __restrict__ qWb) {
  int h = blockIdx.x, t = threadIdx.x, lane = t & 63, wid = t >> 6;
  float gs = 0.f, bb = 0.f;
  for (int c = t; c < CC; c += 256) {
    gs += qWg[h * CC + c];
    bb += qW[h * CC + c] * kvb[c];
  }
  gs = wsum(gs);
  bb = wsum(bb);
  __shared__ float red[8];
  if (lane == 0) { red[wid] = gs; red[4 + wid] = bb; }
  __syncthreads();
  if (t == 0) {
    qWgs[h] = red[0] + red[1] + red[2] + red[3];
    qWb[h] = red[4] + red[5] + red[6] + red[7];
  }
}

// ---- fused single pass over x ----
__global__ __launch_bounds__(256, 4) void kfused(
    const float* __restrict__ x, const float* __restrict__ qWg,
    const float* __restrict__ qWgs, const float* __restrict__ qWb,
    float* __restrict__ part_s, float* __restrict__ part_meu) {
  __shared__ __align__(16) float xbuf[2][TPT * CC];  // 2 x 16 KB
  __shared__ __align__(16) float w_lds[HH * TPT];    // [h][r]
  __shared__ __align__(16) float fac_lds[HH];
  __shared__ float mu_lds[TPT], rstd_lds[TPT];

  const int t = threadIdx.x, lane = t & 63, wid = t >> 6;
  const int chunk = blockIdx.x, b = blockIdx.y;
  const int bc = b * CHUNKS + chunk;
  const int h0 = wid * 2;

  // this wave's two heads' qWg fragments (cols 4*(lane+64k)..+3)
  float4 qw0[4], qw1[4];
  {
    const float4* a0 = (const float4*)(qWg + (size_t)h0 * CC);
    const float4* a1 = (const float4*)(qWg + (size_t)(h0 + 1) * CC);
#pragma unroll
    for (int k = 0; k < 4; ++k) { qw0[k] = a0[lane + 64 * k]; qw1[k] = a1[lane + 64 * k]; }
  }
  const float qs0 = qWgs[h0], qs1 = qWgs[h0 + 1];
  const float qb0 = qWb[h0], qb1 = qWb[h0 + 1];

  float4 acc[8];
#pragma unroll
  for (int h = 0; h < 8; ++h) acc[h] = make_float4(0.f, 0.f, 0.f, 0.f);
  float m0 = -3.0e38f, m1 = -3.0e38f, e0 = 0.f, e1 = 0.f, un0 = 0.f, un1 = 0.f;

  const float* gx = x + ((size_t)b * NN + (size_t)chunk * RPB) * CC;

  // prologue: stage tile 0
  stage_tile(gx, xbuf[0], wid, lane);

  for (int tl = 0; tl < NT; ++tl) {
    const int cur = tl & 1;
    bar_vm();  // current tile landed (issued a full tile ago); prev buffer free

    if (tl + 1 < NT)
      stage_tile(gx + (size_t)(tl + 1) * (TPT * CC), xbuf[cur ^ 1], wid, lane);

    const float4* xb4 = (const float4*)xbuf[cur];

    // ---- DOT: this wave's 2 heads for all 4 rows; stats for row==wid
    float d0[TPT], d1[TPT];
#pragma unroll
    for (int r = 0; r < TPT; ++r) {
      float4 x0 = xb4[r * 256 + lane];
      float4 x1 = xb4[r * 256 + lane + 64];
      float4 x2 = xb4[r * 256 + lane + 128];
      float4 x3 = xb4[r * 256 + lane + 192];
      float s0 = dot4(qw0[0], x0) + dot4(qw0[1], x1) + dot4(qw0[2], x2) + dot4(qw0[3], x3);
      float s1 = dot4(qw1[0], x0) + dot4(qw1[1], x1) + dot4(qw1[2], x2) + dot4(qw1[3], x3);
      d0[r] = dpp_sum63(s0);
      d1[r] = dpp_sum63(s1);
      if (r == wid) {
        float ls = (x0.x + x0.y + x0.z + x0.w) + (x1.x + x1.y + x1.z + x1.w) +
                   (x2.x + x2.y + x2.z + x2.w) + (x3.x + x3.y + x3.z + x3.w);
        float ls2 = dot4(x0, x0) + dot4(x1, x1) + dot4(x2, x2) + dot4(x3, x3);
        ls = dpp_sum63(ls);
        ls2 = dpp_sum63(ls2);
        if (lane == 63) {
          float mu = ls * (1.f / CC);
          float rs = rsqrtf(ls2 * (1.f / CC) - mu * mu + EPS_);
          mu_lds[r] = mu;
          rstd_lds[r] = rs;
        }
      }
    }
    bar_lgkm();

    // ---- W phase: lane 63 of each wave finalizes its 2 heads (dots live here)
    if (lane == 63) {
      float mu[TPT], rs[TPT];
#pragma unroll
      for (int r = 0; r < TPT; ++r) { mu[r] = mu_lds[r]; rs[r] = rstd_lds[r]; }
      float l0[TPT], l1[TPT];
      float tm0 = -3.0e38f, tm1 = -3.0e38f;
#pragma unroll
      for (int r = 0; r < TPT; ++r) {
        l0[r] = rs[r] * (d0[r] - mu[r] * qs0) + qb0; tm0 = fmaxf(tm0, l0[r]);
        l1[r] = rs[r] * (d1[r] - mu[r] * qs1) + qb1; tm1 = fmaxf(tm1, l1[r]);
      }
      float f0 = 1.f, f1 = 1.f;
      if (tm0 > m0 + 8.f) { f0 = __expf(m0 - tm0); m0 = tm0; e0 *= f0; un0 *= f0; }
      if (tm1 > m1 + 8.f) { f1 = __expf(m1 - tm1); m1 = tm1; e1 *= f1; un1 *= f1; }
      fac_lds[h0] = f0;
      fac_lds[h0 + 1] = f1;
#pragma unroll
      for (int r = 0; r < TPT; ++r) {
        float p0 = __expf(l0[r] - m0), p1 = __expf(l1[r] - m1);
        float w0 = p0 * rs[r], w1 = p1 * rs[r];
        e0 += p0; e1 += p1;
        un0 += w0 * mu[r]; un1 += w1 * mu[r];
        w_lds[h0 * TPT + r] = w0;
        w_lds[(h0 + 1) * TPT + r] = w1;
      }
    }
    bar_lgkm();

    // ---- ACC: thread owns cols 4t..4t+3, all 8 heads
    {
      float4 fA = *(const float4*)&fac_lds[0];
      float4 fB = *(const float4*)&fac_lds[4];
      scl4(acc[0], fA.x); scl4(acc[1], fA.y); scl4(acc[2], fA.z); scl4(acc[3], fA.w);
      scl4(acc[4], fB.x); scl4(acc[5], fB.y); scl4(acc[6], fB.z); scl4(acc[7], fB.w);
      float4 xv0 = xb4[t];
      float4 xv1 = xb4[256 + t];
      float4 xv2 = xb4[512 + t];
      float4 xv3 = xb4[768 + t];
      const float4* wp = (const float4*)w_lds;  // [h] -> 4 rows
#pragma unroll
      for (int h = 0; h < 8; ++h) {
        float4 w = wp[h];
        fma4(acc[h], w.x, xv0);
        fma4(acc[h], w.y, xv1);
        fma4(acc[h], w.z, xv2);
        fma4(acc[h], w.w, xv3);
      }
    }
  }

  // ---- store partials
  float4* ps = (float4*)(part_s + (size_t)bc * (HH * CC));
#pragma unroll
  for (int h = 0; h < 8; ++h) ps[h * 256 + t] = acc[h];
  if (lane == 63) {
    float* pm = part_meu + ((size_t)bc * HH + h0) * 3;
    pm[0] = m0; pm[1] = e0; pm[2] = un0;
    pm[3] = m1; pm[4] = e1; pm[5] = un1;
  }
}

// ---- merge partials: s[b,h,c] = gamma*(S-UN)/E + beta ----
__global__ __launch_bounds__(256) void kmerge(
    const float* __restrict__ part_s, const float* __restrict__ part_meu,
    const float* __restrict__ kvg, const float* __restrict__ kvb,
    float* __restrict__ s) {
  int h = blockIdx.x >> 2, q = blockIdx.x & 3, b = blockIdx.y;
  int col = q * 256 + threadIdx.x;
  float M = -3.0e38f;
  for (int ch = 0; ch < CHUNKS; ++ch)
    M = fmaxf(M, part_meu[(((size_t)b * CHUNKS + ch) * HH + h) * 3]);
  float E = 0.f, UN = 0.f, a = 0.f;
  for (int ch = 0; ch < CHUNKS; ++ch) {
    const float* pm = part_meu + (((size_t)b * CHUNKS + ch) * HH + h) * 3;
    float f = __expf(pm[0] - M);
    E += pm[1] * f;
    UN += pm[2] * f;
    a += f * part_s[(((size_t)b * CHUNKS + ch) * HH + h) * CC + col];
  }
  float inv = 1.f / E;
  s[((size_t)b * HH + h) * CC + col] = kvg[col] * (a - UN) * inv + kvb[col];
}

// ---- k5: agg[b,j] = Wkv[C+j,:] . s[b, j/D, :] ----
__global__ __launch_bounds__(256) void k5(const float* __restrict__ Wkv,
                                          const float* __restrict__ s,
                                          float* __restrict__ agg) {
  int lane = threadIdx.x & 63;
  int j = blockIdx.x * 4 + (threadIdx.x >> 6);
  int h = j >> 7;
  const float4* wr = (const float4*)(Wkv + ((size_t)(CC + j)) * CC);
  float4 wv[4];
#pragma unroll
  for (int k = 0; k < 4; ++k) wv[k] = wr[lane + 64 * k];
  for (int b = 0; b < BB; ++b) {
    const float4* s4 = (const float4*)(s + ((size_t)(b * HH + h)) * CC);
    float a = 0.f;
#pragma unroll
    for (int k = 0; k < 4; ++k) a += dot4(wv[k], s4[lane + 64 * k]);
    a = wsum(a);
    if (lane == 0) agg[b * CC + j] = a;
  }
}

// ---- k6: out[b,j] = cf[j] + agg[b,:] . proj_W[j,:] + proj_b[j] ----
__global__ __launch_bounds__(256) void k6(const float* __restrict__ pW,
                                          const float* __restrict__ agg,
                                          const float* __restrict__ cf,
                                          const float* __restrict__ pb,
                                          float* __restrict__ out) {
  int lane = threadIdx.x & 63;
  int j = blockIdx.x * 4 + (threadIdx.x >> 6);
  const float4* wr = (const float4*)(pW + (size_t)j * CC);
  float4 wv[4];
#pragma unroll
  for (int k = 0; k < 4; ++k) wv[k] = wr[lane + 64 * k];
  for (int b = 0; b < BB; ++b) {
    const float4* a4 = (const float4*)(agg + (size_t)b * CC);
    float a = 0.f;
#pragma unroll
    for (int k = 0; k < 4; ++k) a += dot4(wv[k], a4[lane + 64 * k]);
    a = wsum(a);
    if (lane == 0) out[b * CC + j] = cf[j] + a + pb[j];
  }
}

// ws float offsets
constexpr size_t WS_LNCF = 0;        // 1024
constexpr size_t WS_QVEC = 1024;     // 1024
constexpr size_t WS_QW   = 2048;     // 8192
constexpr size_t WS_QWG  = 10240;    // 8192
constexpr size_t WS_QWGS = 18432;    // 8
constexpr size_t WS_QWB  = 18440;    // 8
constexpr size_t WS_S    = 18448;    // 131072
constexpr size_t WS_AGG  = 149520;   // 16384
constexpr size_t WS_PMEU = 165904;   // 24576
constexpr size_t WS_PART = 190480;   // 8388608 (33.5 MB)

extern "C" void kernel_launch(void* const* d_in, const int* in_sizes, int n_in,
                              void* d_out, int out_size, void* d_ws, size_t ws_size,
                              hipStream_t stream) {
  const float* cf = (const float*)d_in[0];
  const float* x = (const float*)d_in[1];
  const float* qg = (const float*)d_in[2];
  const float* qb = (const float*)d_in[3];
  const float* Wq = (const float*)d_in[4];
  const float* kvg = (const float*)d_in[5];
  const float* kvb = (const float*)d_in[6];
  const float* Wkv = (const float*)d_in[7];
  const float* pW = (const float*)d_in[8];
  const float* pb = (const float*)d_in[9];
  float* ws = (float*)d_ws;
  float* out = (float*)d_out;

  k0a<<<1, 256, 0, stream>>>(cf, qg, qb, ws + WS_LNCF);
  k0b<<<256, 256, 0, stream>>>(ws + WS_LNCF, Wq, ws + WS_QVEC);
  k0c<<<128, 256, 0, stream>>>(ws + WS_QVEC, Wkv, kvg, ws + WS_QW, ws + WS_QWG);
  k0d<<<8, 256, 0, stream>>>(ws + WS_QW, ws + WS_QWG, kvb, ws + WS_QWGS, ws + WS_QWB);
  kfused<<<dim3(CHUNKS, BB), 256, 0, stream>>>(x, ws + WS_QWG, ws + WS_QWGS,
                                               ws + WS_QWB, ws + WS_PART, ws + WS_PMEU);
  kmerge<<<dim3(HH * 4, BB), 256, 0, stream>>>(ws + WS_PART, ws + WS_PMEU, kvg, kvb,
                                               ws + WS_S);
  k5<<<256, 256, 0, stream>>>(Wkv, ws + WS_S, ws + WS_AGG);
  k6<<<256, 256, 0, stream>>>(pW, ws + WS_AGG, cf, pb, out);
}